// Round 13
// baseline (350.310 us; speedup 1.0000x reference)
//
#include <hip/hip_runtime.h>

#define BS 4096
#define NV 778
#define NJ 16
#define NC 45

// ws float offsets
#define WS_JRS   0                       // 480 floats: (JR@shapedirs)[j,d,s]
#define WS_JRVT  480                     // 48 floats:  (JR@v_template)[j,d]
#define WS_SE3   528                     // BS*192
#define WS_AT    (528 + BS*192)          // 148*BS, layout [k][b]: k<135 pose-feat,
                                         // 135..144 shape, 145 ones, 146..147 zeros
#define WS_SHIFT (WS_AT + 148*BS)        // BS*4, trans - center

// ---------------- kernel A: batch-independent precompute ----------------
__global__ __launch_bounds__(64) void mano_pre(
    const float* __restrict__ shapedirs, const float* __restrict__ v_template,
    const float* __restrict__ JR, float* __restrict__ ws)
{
    int o = blockIdx.x;          // 0..527
    int lane = threadIdx.x;
    float acc = 0.0f;
    if (o < 480) {
        int j = o / 30, rem = o % 30;
        for (int v = lane; v < NV; v += 64)
            acc += JR[j * NV + v] * shapedirs[v * 30 + rem];
    } else {
        int o2 = o - 480;
        int j = o2 / 3, d = o2 % 3;
        for (int v = lane; v < NV; v += 64)
            acc += JR[j * NV + v] * v_template[v * 3 + d];
    }
    #pragma unroll
    for (int off = 32; off > 0; off >>= 1) acc += __shfl_down(acc, off, 64);
    if (lane == 0) ws[(o < 480) ? (WS_JRS + o) : (WS_JRVT + (o - 480))] = acc;
}

// ---------------- kernel B: per-batch prep (1 wave / batch) ----------------
// R5-verbatim. R6 split and R9 4x-packing were both neutral.
__global__ __launch_bounds__(64) void mano_batch(
    const float* __restrict__ root_rot, const float* __restrict__ pose,
    const float* __restrict__ shape, const float* __restrict__ trans,
    const float* __restrict__ hc, const float* __restrict__ hmean,
    float* __restrict__ ws, float* __restrict__ out)
{
    const int b = blockIdx.x;
    const int t = threadIdx.x;

    __shared__ float s_pose[NC], s_shape[10], s_axis[NC];
    __shared__ float s_rot[135], s_pf[135];
    __shared__ float s_jt[48], s_A[192], s_SE3[192], s_jl[48], s_shift[3];

    if (t < NC) s_pose[t] = pose[b * NC + t];
    if (t < 10) s_shape[t] = shape[b * 10 + t];
    __syncthreads();

    if (t < NC) {
        float a = hmean[t];
        for (int i = 0; i < NC; ++i) a += s_pose[i] * hc[i * NC + t];
        s_axis[t] = a;
    }
    __syncthreads();

    if (t < 15) {   // Rodrigues
        float ax = s_axis[t*3+0], ay = s_axis[t*3+1], az = s_axis[t*3+2];
        float angle = sqrtf(ax*ax + ay*ay + az*az + 1e-12f);
        float inv = 1.0f / angle;
        float ux = ax*inv, uy = ay*inv, uz = az*inv;
        float c = cosf(angle), s = sinf(angle), ic = 1.0f - c;
        float R[9];
        R[0]=c+ic*ux*ux;       R[1]=-s*uz+ic*ux*uy;  R[2]= s*uy+ic*ux*uz;
        R[3]= s*uz+ic*ux*uy;   R[4]=c+ic*uy*uy;      R[5]=-s*ux+ic*uy*uz;
        R[6]=-s*uy+ic*ux*uz;   R[7]= s*ux+ic*uy*uz;  R[8]=c+ic*uz*uz;
        #pragma unroll
        for (int k = 0; k < 9; ++k) {
            s_rot[t*9+k] = R[k];
            s_pf[t*9+k]  = R[k] - ((k==0||k==4||k==8) ? 1.0f : 0.0f);
        }
    }
    if (t < 48) {   // j_tpose via (JR@shapedirs) trick
        float a = ws[WS_JRVT + t];
        #pragma unroll
        for (int s2 = 0; s2 < 10; ++s2) a += ws[WS_JRS + t*10 + s2] * s_shape[s2];
        s_jt[t] = a;
    }
    __syncthreads();

    if (t < NJ) {   // local [R | j - R j]
        float R[9];
        if (t == 0) {
            #pragma unroll
            for (int k = 0; k < 9; ++k) R[k] = root_rot[b*9+k];
        } else {
            #pragma unroll
            for (int k = 0; k < 9; ++k) R[k] = s_rot[(t-1)*9+k];
        }
        float jx = s_jt[t*3+0], jy = s_jt[t*3+1], jz = s_jt[t*3+2];
        #pragma unroll
        for (int r = 0; r < 3; ++r) {
            float jr = (r==0)?jx:((r==1)?jy:jz);
            float ti = jr - (R[r*3+0]*jx + R[r*3+1]*jy + R[r*3+2]*jz);
            s_A[t*12+r*4+0]=R[r*3+0]; s_A[t*12+r*4+1]=R[r*3+1];
            s_A[t*12+r*4+2]=R[r*3+2]; s_A[t*12+r*4+3]=ti;
        }
    }
    __syncthreads();

    if (t == 5) {
        #pragma unroll
        for (int k = 0; k < 12; ++k) s_SE3[k] = s_A[k];
    }
    if (t < 5) {    // 5 chains of depth 3
        float P[12];
        #pragma unroll
        for (int k = 0; k < 12; ++k) P[k] = s_A[k];
        for (int step = 0; step < 3; ++step) {
            int i = t*3 + 1 + step;
            float M[12];
            #pragma unroll
            for (int r = 0; r < 3; ++r) {
                #pragma unroll
                for (int c = 0; c < 3; ++c)
                    M[r*4+c] = P[r*4+0]*s_A[i*12+0*4+c] + P[r*4+1]*s_A[i*12+1*4+c]
                             + P[r*4+2]*s_A[i*12+2*4+c];
                M[r*4+3] = P[r*4+0]*s_A[i*12+3] + P[r*4+1]*s_A[i*12+7]
                         + P[r*4+2]*s_A[i*12+11] + P[r*4+3];
            }
            #pragma unroll
            for (int k = 0; k < 12; ++k) { s_SE3[i*12+k] = M[k]; P[k] = M[k]; }
        }
    }
    __syncthreads();

    if (t < NJ) {   // posed joints
        if (t == 0) { s_jl[0]=s_jt[0]; s_jl[1]=s_jt[1]; s_jl[2]=s_jt[2]; }
        else {
            const int PAR[NJ] = {-1,0,1,2,0,4,5,0,7,8,0,10,11,0,13,14};
            int p = PAR[t];
            float jx = s_jt[t*3+0], jy = s_jt[t*3+1], jz = s_jt[t*3+2];
            #pragma unroll
            for (int r = 0; r < 3; ++r)
                s_jl[t*3+r] = s_SE3[p*12+r*4+0]*jx + s_SE3[p*12+r*4+1]*jy
                            + s_SE3[p*12+r*4+2]*jz + s_SE3[p*12+r*4+3];
        }
    }
    if (t < 3) s_shift[t] = trans[b*3+t] - s_jt[t];
    __syncthreads();

    // ---- stores ----
    for (int k = t; k < 148; k += 64) {
        float val;
        if (k < 135)       val = s_pf[k];
        else if (k < 145)  val = s_shape[k - 135];
        else if (k == 145) val = 1.0f;
        else               val = 0.0f;
        ws[WS_AT + k*BS + b] = val;
    }
    for (int k = t; k < 192; k += 64) ws[WS_SE3 + b*192 + k] = s_SE3[k];
    if (t < 4) ws[WS_SHIFT + b*4 + t] = (t < 3) ? s_shift[t] : 0.0f;
    if (t < 21) {
        const int NO[21] = {0,13,14,15,16,1,2,3,17,4,5,6,18,10,11,12,19,7,8,9,20};
        int src = NO[t];
        if (src < 16) {
            size_t jb = (size_t)BS*2334 + (size_t)b*63 + (size_t)t*3;
            out[jb+0] = s_jl[src*3+0] + s_shift[0];
            out[jb+1] = s_jl[src*3+1] + s_shift[1];
            out[jb+2] = s_jl[src*3+2] + s_shift[2];
        }
    }
}

// ---------------- kernel C: GEMM (K=148) + fused LBS ----------------
// Block: 64 batches x 64 VERTICES. Thread: 4 batches x 4 ADJACENT vertices.
// R12 accounting: verts was LDS-pipe bound (~75us of 111) with GEMM reads
// dominant (370/600 per thread) and VGPR only 68/168 -> register tile was
// undersized. This tile: 16 reads/192 FMA in GEMM; epilogue's S-reads serve
// 4 verts; weights read as ONE float4/j from transposed s_wT. K staged in
// 4 quarters (10/9/9/9 groups) so LDS = union(As+Bs, Ss)+s_wT = 53.5KB ->
// still 3 blocks/CU. Epilogue j-loop rotated per-bq (jr=(j+bq)&15) to break
// the stride-768 16-way bank conflict (M-sum reorder ~1e-6 << threshold).
// NOTE 1: NO min-occupancy arg in __launch_bounds__ (rounds 1/3: spill).
// NOTE 2: '#pragma unroll 1' on K/quarter loops is LOAD-BEARING (round 4).
// NOTE 3: do NOT hand-pipeline the GEMM loop (round 8: 125->157us).
// NOTE 4: SE3 goes through LDS, NOT global-direct (round 10: 125->136us).
// NOTE 5: VGPR gate: must stay <=168 for 3 waves/SIMD (round 11: 180 -> 11%).
#define AS_LD 68        // A row stride (floats): 64 data + 4 pad
#define BS_LD 44        // B col stride (floats): 40 rows max + 4 pad (bank-offset)
#define SS_LD 192       // SE3 row stride per batch (== source, straight copy)
#define WT_LD 68        // s_wT row stride (floats): 64 + 4 pad (bank-offset)

__global__ __launch_bounds__(256) void mano_verts(
    const float* __restrict__ posedirs, const float* __restrict__ shapedirs,
    const float* __restrict__ v_template, const float* __restrict__ weights,
    const float* __restrict__ ws, float* __restrict__ out)
{
    const int btile = blockIdx.x;   // 0..63
    const int vtile = blockIdx.y;   // 0..12
    const int t = threadIdx.x;
    const int b0 = btile * 64;
    const int v0 = vtile * 64;

    __shared__ union {
        struct { float As[40*AS_LD]; float Bs[192*BS_LD]; } g; // 10880+33792 B
        float Ss[64*SS_LD];                                    // 49152 B
    } u;
    __shared__ float s_wT[16*WT_LD];   // weights TRANSPOSED: [joint][vert], 4352 B

    // ---- stage weights transposed: s_wT[j][vl] ----
    for (int idx = t; idx < 16*64; idx += 256) {
        int vl = idx & 63, j = idx >> 6;
        int vg = v0 + vl; if (vg > NV-1) vg = NV-1;
        s_wT[j*WT_LD + vl] = weights[vg*16 + j];
    }

    const int vi = t & 15, bq = t >> 4;     // bq in 0..15 now
    const int bq4 = bq * 4, vi4 = vi * 4;
    const float* At = ws + WS_AT + b0;

    float acc[4][4][3];   // [ib][m][c]
    #pragma unroll
    for (int i = 0; i < 4; ++i)
        #pragma unroll
        for (int m = 0; m < 4; ++m)
            #pragma unroll
            for (int c = 0; c < 3; ++c) acc[i][m][c] = 0.0f;

    // ============ four K-quarters: stage A+B, then GEMM ============
    #pragma unroll 1
    for (int q = 0; q < 4; ++q) {
        const int r0 = q ? (36*q + 4) : 0;   // 0,40,76,112
        const int nq = q ? 9 : 10;           // float4 groups this quarter
        const int nr = nq * 4;               // rows this quarter

        // ---- stage B: 192 cols x nq groups (const-divisor layout) ----
        for (int idx = t; idx < 192*10; idx += 256) {
            int col = idx / 10, kq = idx - col*10;
            if (kq < nq) {
                int kk = kq * 4;
                int vg = v0 + col/3; if (vg > NV-1) vg = NV-1;
                int d = col % 3;
                float tmp[4];
                #pragma unroll
                for (int uu = 0; uu < 4; ++uu) {
                    int k = r0 + kk + uu;
                    float x;
                    if (k < 135)       x = posedirs[vg*405 + d*135 + k];
                    else if (k < 145)  x = shapedirs[vg*30 + d*10 + (k-135)];
                    else if (k == 145) x = v_template[vg*3 + d];
                    else               x = 0.0f;
                    tmp[uu] = x;
                }
                *(float4*)&u.g.Bs[col*BS_LD + kk] =
                    make_float4(tmp[0], tmp[1], tmp[2], tmp[3]);
            }
        }
        // ---- stage A: nr rows, float4 over batches ----
        for (int idx = t; idx < 40*16; idx += 256) {
            int kr = idx >> 4, j4 = (idx & 15) << 2;
            if (kr < nr)
                *(float4*)&u.g.As[kr*AS_LD + j4] =
                    *(const float4*)&At[(size_t)(r0+kr)*BS + j4];
        }
        __syncthreads();

        // ---- GEMM over this quarter ----
        #pragma unroll 1
        for (int r = 0; r < nq; ++r) {
            const int kk = r * 4;
            float a_[4][4];   // a_[kq][ib]
            #pragma unroll
            for (int kq = 0; kq < 4; ++kq)
                *(float4*)&a_[kq][0] = *(const float4*)&u.g.As[(kk+kq)*AS_LD + bq4];
            #pragma unroll
            for (int m = 0; m < 4; ++m) {
                float b_[3][4];   // [c][kq]
                #pragma unroll
                for (int c = 0; c < 3; ++c)
                    *(float4*)&b_[c][0] =
                        *(const float4*)&u.g.Bs[((vi4+m)*3+c)*BS_LD + kk];
                #pragma unroll
                for (int ib = 0; ib < 4; ++ib)
                    #pragma unroll
                    for (int c = 0; c < 3; ++c)
                        acc[ib][m][c] += a_[0][ib]*b_[c][0] + a_[1][ib]*b_[c][1]
                                       + a_[2][ib]*b_[c][2] + a_[3][ib]*b_[c][3];
            }
        }
        __syncthreads();
    }

    // ---- stage SE3 tile: SS_LD == source stride 192 -> straight float4 copy ----
    const float* se3w = ws + WS_SE3 + (size_t)b0*192;
    for (int idx = t; idx < 64*48; idx += 256)
        *(float4*)&u.Ss[idx << 2] = *(const float4*)&se3w[idx << 2];
    __syncthreads();

    // ---- LBS epilogue: S-reads serve 4 vertices; w as one float4 per j ----
    #pragma unroll
    for (int ib = 0; ib < 4; ++ib) {
        const int bl = bq4 + ib;
        const int bg = b0 + bl;
        const float* S = &u.Ss[bl*SS_LD];
        float M[4][12];
        #pragma unroll
        for (int m = 0; m < 4; ++m)
            #pragma unroll
            for (int k = 0; k < 12; ++k) M[m][k] = 0.0f;
        #pragma unroll 2
        for (int j = 0; j < 16; ++j) {
            int jr = (j + bq) & 15;            // per-bq rotation: kills 16-way conflict
            float4 r0v = *(const float4*)&S[jr*12 + 0];
            float4 r1v = *(const float4*)&S[jr*12 + 4];
            float4 r2v = *(const float4*)&S[jr*12 + 8];
            float4 w4  = *(const float4*)&s_wT[jr*WT_LD + vi4];
            float wm[4] = {w4.x, w4.y, w4.z, w4.w};
            #pragma unroll
            for (int m = 0; m < 4; ++m) {
                float w = wm[m];
                M[m][0] += w*r0v.x; M[m][1] += w*r0v.y; M[m][2]  += w*r0v.z; M[m][3]  += w*r0v.w;
                M[m][4] += w*r1v.x; M[m][5] += w*r1v.y; M[m][6]  += w*r1v.z; M[m][7]  += w*r1v.w;
                M[m][8] += w*r2v.x; M[m][9] += w*r2v.y; M[m][10] += w*r2v.z; M[m][11] += w*r2v.w;
            }
        }
        float sh0 = ws[WS_SHIFT + bg*4 + 0];
        float sh1 = ws[WS_SHIFT + bg*4 + 1];
        float sh2 = ws[WS_SHIFT + bg*4 + 2];
        #pragma unroll
        for (int m = 0; m < 4; ++m) {
            const int vg = v0 + vi4 + m;
            float x = acc[ib][m][0], y = acc[ib][m][1], z = acc[ib][m][2];
            float ox = M[m][0]*x + M[m][1]*y + M[m][2] *z + M[m][3]  + sh0;
            float oy = M[m][4]*x + M[m][5]*y + M[m][6] *z + M[m][7]  + sh1;
            float oz = M[m][8]*x + M[m][9]*y + M[m][10]*z + M[m][11] + sh2;
            if (vg < NV) {
                size_t o = (size_t)bg*2334 + (size_t)vg*3;
                out[o+0] = ox; out[o+1] = oy; out[o+2] = oz;
                int slot = -1;
                if (vg == 745) slot = 4; else if (vg == 333) slot = 8;
                else if (vg == 444) slot = 12; else if (vg == 555) slot = 16;
                else if (vg == 672) slot = 20;
                if (slot >= 0) {
                    size_t jb = (size_t)BS*2334 + (size_t)bg*63 + (size_t)slot*3;
                    out[jb+0] = ox; out[jb+1] = oy; out[jb+2] = oz;
                }
            }
        }
    }
}

extern "C" void kernel_launch(void* const* d_in, const int* in_sizes, int n_in,
                              void* d_out, int out_size, void* d_ws, size_t ws_size,
                              hipStream_t stream) {
    (void)in_sizes; (void)n_in; (void)ws_size; (void)out_size;
    const float* root_rot   = (const float*)d_in[0];
    const float* pose       = (const float*)d_in[1];
    const float* shape      = (const float*)d_in[2];
    const float* trans      = (const float*)d_in[3];
    const float* hc         = (const float*)d_in[4];
    const float* hmean      = (const float*)d_in[5];
    const float* shapedirs  = (const float*)d_in[6];
    const float* posedirs   = (const float*)d_in[7];
    const float* v_template = (const float*)d_in[8];
    const float* JR         = (const float*)d_in[9];
    const float* weights    = (const float*)d_in[10];
    float* ws  = (float*)d_ws;
    float* out = (float*)d_out;

    mano_pre<<<dim3(528), dim3(64), 0, stream>>>(shapedirs, v_template, JR, ws);
    mano_batch<<<dim3(BS), dim3(64), 0, stream>>>(root_rot, pose, shape, trans,
                                                  hc, hmean, ws, out);
    mano_verts<<<dim3(64, 13), dim3(256), 0, stream>>>(posedirs, shapedirs, v_template,
                                                       weights, ws, out);
}

// Round 14
// 231.861 us; speedup vs baseline: 1.5109x; 1.5109x over previous
//
#include <hip/hip_runtime.h>

#define BS 4096
#define NV 778
#define NJ 16
#define NC 45

// ws float offsets
#define WS_JRS   0                       // 480 floats: (JR@shapedirs)[j,d,s]
#define WS_JRVT  480                     // 48 floats:  (JR@v_template)[j,d]
#define WS_SE3   528                     // BS*192
#define WS_AT    (528 + BS*192)          // 148*BS, layout [k][b]: k<135 pose-feat,
                                         // 135..144 shape, 145 ones, 146..147 zeros
#define WS_SHIFT (WS_AT + 148*BS)        // BS*4, trans - center

// ---------------- kernel A: batch-independent precompute ----------------
__global__ __launch_bounds__(64) void mano_pre(
    const float* __restrict__ shapedirs, const float* __restrict__ v_template,
    const float* __restrict__ JR, float* __restrict__ ws)
{
    int o = blockIdx.x;          // 0..527
    int lane = threadIdx.x;
    float acc = 0.0f;
    if (o < 480) {
        int j = o / 30, rem = o % 30;
        for (int v = lane; v < NV; v += 64)
            acc += JR[j * NV + v] * shapedirs[v * 30 + rem];
    } else {
        int o2 = o - 480;
        int j = o2 / 3, d = o2 % 3;
        for (int v = lane; v < NV; v += 64)
            acc += JR[j * NV + v] * v_template[v * 3 + d];
    }
    #pragma unroll
    for (int off = 32; off > 0; off >>= 1) acc += __shfl_down(acc, off, 64);
    if (lane == 0) ws[(o < 480) ? (WS_JRS + o) : (WS_JRVT + (o - 480))] = acc;
}

// ---------------- kernel B: per-batch prep (1 wave / batch) ----------------
// R5-verbatim. R6 split and R9 4x-packing were both neutral.
__global__ __launch_bounds__(64) void mano_batch(
    const float* __restrict__ root_rot, const float* __restrict__ pose,
    const float* __restrict__ shape, const float* __restrict__ trans,
    const float* __restrict__ hc, const float* __restrict__ hmean,
    float* __restrict__ ws, float* __restrict__ out)
{
    const int b = blockIdx.x;
    const int t = threadIdx.x;

    __shared__ float s_pose[NC], s_shape[10], s_axis[NC];
    __shared__ float s_rot[135], s_pf[135];
    __shared__ float s_jt[48], s_A[192], s_SE3[192], s_jl[48], s_shift[3];

    if (t < NC) s_pose[t] = pose[b * NC + t];
    if (t < 10) s_shape[t] = shape[b * 10 + t];
    __syncthreads();

    if (t < NC) {
        float a = hmean[t];
        for (int i = 0; i < NC; ++i) a += s_pose[i] * hc[i * NC + t];
        s_axis[t] = a;
    }
    __syncthreads();

    if (t < 15) {   // Rodrigues
        float ax = s_axis[t*3+0], ay = s_axis[t*3+1], az = s_axis[t*3+2];
        float angle = sqrtf(ax*ax + ay*ay + az*az + 1e-12f);
        float inv = 1.0f / angle;
        float ux = ax*inv, uy = ay*inv, uz = az*inv;
        float c = cosf(angle), s = sinf(angle), ic = 1.0f - c;
        float R[9];
        R[0]=c+ic*ux*ux;       R[1]=-s*uz+ic*ux*uy;  R[2]= s*uy+ic*ux*uz;
        R[3]= s*uz+ic*ux*uy;   R[4]=c+ic*uy*uy;      R[5]=-s*ux+ic*uy*uz;
        R[6]=-s*uy+ic*ux*uz;   R[7]= s*ux+ic*uy*uz;  R[8]=c+ic*uz*uz;
        #pragma unroll
        for (int k = 0; k < 9; ++k) {
            s_rot[t*9+k] = R[k];
            s_pf[t*9+k]  = R[k] - ((k==0||k==4||k==8) ? 1.0f : 0.0f);
        }
    }
    if (t < 48) {   // j_tpose via (JR@shapedirs) trick
        float a = ws[WS_JRVT + t];
        #pragma unroll
        for (int s2 = 0; s2 < 10; ++s2) a += ws[WS_JRS + t*10 + s2] * s_shape[s2];
        s_jt[t] = a;
    }
    __syncthreads();

    if (t < NJ) {   // local [R | j - R j]
        float R[9];
        if (t == 0) {
            #pragma unroll
            for (int k = 0; k < 9; ++k) R[k] = root_rot[b*9+k];
        } else {
            #pragma unroll
            for (int k = 0; k < 9; ++k) R[k] = s_rot[(t-1)*9+k];
        }
        float jx = s_jt[t*3+0], jy = s_jt[t*3+1], jz = s_jt[t*3+2];
        #pragma unroll
        for (int r = 0; r < 3; ++r) {
            float jr = (r==0)?jx:((r==1)?jy:jz);
            float ti = jr - (R[r*3+0]*jx + R[r*3+1]*jy + R[r*3+2]*jz);
            s_A[t*12+r*4+0]=R[r*3+0]; s_A[t*12+r*4+1]=R[r*3+1];
            s_A[t*12+r*4+2]=R[r*3+2]; s_A[t*12+r*4+3]=ti;
        }
    }
    __syncthreads();

    if (t == 5) {
        #pragma unroll
        for (int k = 0; k < 12; ++k) s_SE3[k] = s_A[k];
    }
    if (t < 5) {    // 5 chains of depth 3
        float P[12];
        #pragma unroll
        for (int k = 0; k < 12; ++k) P[k] = s_A[k];
        for (int step = 0; step < 3; ++step) {
            int i = t*3 + 1 + step;
            float M[12];
            #pragma unroll
            for (int r = 0; r < 3; ++r) {
                #pragma unroll
                for (int c = 0; c < 3; ++c)
                    M[r*4+c] = P[r*4+0]*s_A[i*12+0*4+c] + P[r*4+1]*s_A[i*12+1*4+c]
                             + P[r*4+2]*s_A[i*12+2*4+c];
                M[r*4+3] = P[r*4+0]*s_A[i*12+3] + P[r*4+1]*s_A[i*12+7]
                         + P[r*4+2]*s_A[i*12+11] + P[r*4+3];
            }
            #pragma unroll
            for (int k = 0; k < 12; ++k) { s_SE3[i*12+k] = M[k]; P[k] = M[k]; }
        }
    }
    __syncthreads();

    if (t < NJ) {   // posed joints
        if (t == 0) { s_jl[0]=s_jt[0]; s_jl[1]=s_jt[1]; s_jl[2]=s_jt[2]; }
        else {
            const int PAR[NJ] = {-1,0,1,2,0,4,5,0,7,8,0,10,11,0,13,14};
            int p = PAR[t];
            float jx = s_jt[t*3+0], jy = s_jt[t*3+1], jz = s_jt[t*3+2];
            #pragma unroll
            for (int r = 0; r < 3; ++r)
                s_jl[t*3+r] = s_SE3[p*12+r*4+0]*jx + s_SE3[p*12+r*4+1]*jy
                            + s_SE3[p*12+r*4+2]*jz + s_SE3[p*12+r*4+3];
        }
    }
    if (t < 3) s_shift[t] = trans[b*3+t] - s_jt[t];
    __syncthreads();

    // ---- stores ----
    for (int k = t; k < 148; k += 64) {
        float val;
        if (k < 135)       val = s_pf[k];
        else if (k < 145)  val = s_shape[k - 135];
        else if (k == 145) val = 1.0f;
        else               val = 0.0f;
        ws[WS_AT + k*BS + b] = val;
    }
    for (int k = t; k < 192; k += 64) ws[WS_SE3 + b*192 + k] = s_SE3[k];
    if (t < 4) ws[WS_SHIFT + b*4 + t] = (t < 3) ? s_shift[t] : 0.0f;
    if (t < 21) {
        const int NO[21] = {0,13,14,15,16,1,2,3,17,4,5,6,18,10,11,12,19,7,8,9,20};
        int src = NO[t];
        if (src < 16) {
            size_t jb = (size_t)BS*2334 + (size_t)b*63 + (size_t)t*3;
            out[jb+0] = s_jl[src*3+0] + s_shift[0];
            out[jb+1] = s_jl[src*3+1] + s_shift[1];
            out[jb+2] = s_jl[src*3+2] + s_shift[2];
        }
    }
}

// ---------------- kernel C: GEMM (K=148) + fused LBS ----------------
// Block: 64 batches x 64 vertices. Thread: 4 batches x 4 STRIDED vertices
// (vi, vi+16, vi+32, vi+48).
// R13 lesson (88M conflicts): ADJACENT vertices make the B-read stride
// 12*BS_LD ≡ 0 or 16 (mod 32) for any float4-aligned BS_LD -> >=8-way
// conflict, unfixable by padding. STRIDED vertices keep the per-vi stride
// at 3*44 = 132 ≡ 4 (mod 32) -> 2-way (free), the proven R12 pattern.
// SS_LD=196 (784 ≡ 16 mod 32 per-wave -> 2-way); R13's 192 was 4-way.
// LDS: union(As+Bs=44672, Ss=50176) + s_wT 4096 = 54272 B = 106*512
// exactly -> 3 blocks/CU at 512B granularity.
// NOTE 1: NO min-occupancy arg in __launch_bounds__ (rounds 1/3: spill).
// NOTE 2: '#pragma unroll 1' on K/quarter loops is LOAD-BEARING (round 4).
// NOTE 3: do NOT hand-pipeline the GEMM loop (round 8: 125->157us).
// NOTE 4: SE3 goes through LDS, NOT global-direct (round 10: 125->136us).
// NOTE 5: VGPR gate <=168 for 3 waves/SIMD (round 11: 180 -> occ 11%).
#define AS_LD 68        // A row stride: 64 data + 4 pad
#define BS_LD 44        // B col stride: 40 rows max + 4 pad; 3*44 ≡ 4 (mod 32)
#define SS_LD 196       // SE3 row stride: 4*196 ≡ 16 (mod 32) per-wave -> 2-way
#define WT_LD 64        // s_wT row stride (scalar reads; vi+m*16 spans banks)

__global__ __launch_bounds__(256) void mano_verts(
    const float* __restrict__ posedirs, const float* __restrict__ shapedirs,
    const float* __restrict__ v_template, const float* __restrict__ weights,
    const float* __restrict__ ws, float* __restrict__ out)
{
    const int btile = blockIdx.x;   // 0..63
    const int vtile = blockIdx.y;   // 0..12
    const int t = threadIdx.x;
    const int b0 = btile * 64;
    const int v0 = vtile * 64;

    __shared__ union {
        struct { float As[40*AS_LD]; float Bs[192*BS_LD]; } g; // 10880+33792 B
        float Ss[64*SS_LD];                                    // 50176 B
    } u;
    __shared__ float s_wT[16*WT_LD];   // weights transposed [joint][vert], 4096 B

    // ---- stage weights transposed: s_wT[j][vl] (contiguous writes) ----
    for (int idx = t; idx < 16*64; idx += 256) {
        int vl = idx & 63, j = idx >> 6;
        int vg = v0 + vl; if (vg > NV-1) vg = NV-1;
        s_wT[j*WT_LD + vl] = weights[vg*16 + j];
    }

    const int vi = t & 15, bq = t >> 4;
    const int bq4 = bq * 4;
    const float* At = ws + WS_AT + b0;

    float acc[4][4][3];   // [ib][m][c], vertex m = v0 + vi + m*16
    #pragma unroll
    for (int i = 0; i < 4; ++i)
        #pragma unroll
        for (int m = 0; m < 4; ++m)
            #pragma unroll
            for (int c = 0; c < 3; ++c) acc[i][m][c] = 0.0f;

    // ============ four K-quarters: stage A+B, then GEMM ============
    #pragma unroll 1
    for (int q = 0; q < 4; ++q) {
        const int r0 = q ? (36*q + 4) : 0;   // 0,40,76,112
        const int nq = q ? 9 : 10;           // float4 groups this quarter
        const int nr = nq * 4;               // rows this quarter

        // ---- stage B: 192 cols x nq groups (const-divisor layout) ----
        for (int idx = t; idx < 192*10; idx += 256) {
            int col = idx / 10, kq = idx - col*10;
            if (kq < nq) {
                int kk = kq * 4;
                int vg = v0 + col/3; if (vg > NV-1) vg = NV-1;
                int d = col % 3;
                float tmp[4];
                #pragma unroll
                for (int uu = 0; uu < 4; ++uu) {
                    int k = r0 + kk + uu;
                    float x;
                    if (k < 135)       x = posedirs[vg*405 + d*135 + k];
                    else if (k < 145)  x = shapedirs[vg*30 + d*10 + (k-135)];
                    else if (k == 145) x = v_template[vg*3 + d];
                    else               x = 0.0f;
                    tmp[uu] = x;
                }
                *(float4*)&u.g.Bs[col*BS_LD + kk] =
                    make_float4(tmp[0], tmp[1], tmp[2], tmp[3]);
            }
        }
        // ---- stage A: nr rows, float4 over batches ----
        for (int idx = t; idx < 40*16; idx += 256) {
            int kr = idx >> 4, j4 = (idx & 15) << 2;
            if (kr < nr)
                *(float4*)&u.g.As[kr*AS_LD + j4] =
                    *(const float4*)&At[(size_t)(r0+kr)*BS + j4];
        }
        __syncthreads();

        // ---- GEMM over this quarter ----
        #pragma unroll 1
        for (int r = 0; r < nq; ++r) {
            const int kk = r * 4;
            float a_[4][4];   // a_[kq][ib]
            #pragma unroll
            for (int kq = 0; kq < 4; ++kq)
                *(float4*)&a_[kq][0] = *(const float4*)&u.g.As[(kk+kq)*AS_LD + bq4];
            #pragma unroll
            for (int m = 0; m < 4; ++m) {
                const int vcol = (vi + m*16) * 3;   // strided vertex
                float b_[3][4];   // [c][kq]
                #pragma unroll
                for (int c = 0; c < 3; ++c)
                    *(float4*)&b_[c][0] =
                        *(const float4*)&u.g.Bs[(vcol+c)*BS_LD + kk];
                #pragma unroll
                for (int ib = 0; ib < 4; ++ib)
                    #pragma unroll
                    for (int c = 0; c < 3; ++c)
                        acc[ib][m][c] += a_[0][ib]*b_[c][0] + a_[1][ib]*b_[c][1]
                                       + a_[2][ib]*b_[c][2] + a_[3][ib]*b_[c][3];
            }
        }
        __syncthreads();
    }

    // ---- stage SE3 tile: Ss[b][196] <- se3w[b][192], float4 copies ----
    const float* se3w = ws + WS_SE3 + (size_t)b0*192;
    for (int idx = t; idx < 64*48; idx += 256) {
        int b = idx / 48, q4 = (idx - b*48) << 2;
        *(float4*)&u.Ss[b*SS_LD + q4] = *(const float4*)&se3w[b*192 + q4];
    }
    __syncthreads();

    // ---- LBS epilogue: S-reads serve 4 vertices ----
    #pragma unroll
    for (int ib = 0; ib < 4; ++ib) {
        const int bl = bq4 + ib;
        const int bg = b0 + bl;
        const float* S = &u.Ss[bl*SS_LD];
        float M[4][12];
        #pragma unroll
        for (int m = 0; m < 4; ++m)
            #pragma unroll
            for (int k = 0; k < 12; ++k) M[m][k] = 0.0f;
        #pragma unroll 2
        for (int j = 0; j < 16; ++j) {
            float4 r0v = *(const float4*)&S[j*12 + 0];
            float4 r1v = *(const float4*)&S[j*12 + 4];
            float4 r2v = *(const float4*)&S[j*12 + 8];
            #pragma unroll
            for (int m = 0; m < 4; ++m) {
                float w = s_wT[j*WT_LD + vi + m*16];
                M[m][0] += w*r0v.x; M[m][1] += w*r0v.y; M[m][2]  += w*r0v.z; M[m][3]  += w*r0v.w;
                M[m][4] += w*r1v.x; M[m][5] += w*r1v.y; M[m][6]  += w*r1v.z; M[m][7]  += w*r1v.w;
                M[m][8] += w*r2v.x; M[m][9] += w*r2v.y; M[m][10] += w*r2v.z; M[m][11] += w*r2v.w;
            }
        }
        float sh0 = ws[WS_SHIFT + bg*4 + 0];
        float sh1 = ws[WS_SHIFT + bg*4 + 1];
        float sh2 = ws[WS_SHIFT + bg*4 + 2];
        #pragma unroll
        for (int m = 0; m < 4; ++m) {
            const int vg = v0 + vi + m*16;
            float x = acc[ib][m][0], y = acc[ib][m][1], z = acc[ib][m][2];
            float ox = M[m][0]*x + M[m][1]*y + M[m][2] *z + M[m][3]  + sh0;
            float oy = M[m][4]*x + M[m][5]*y + M[m][6] *z + M[m][7]  + sh1;
            float oz = M[m][8]*x + M[m][9]*y + M[m][10]*z + M[m][11] + sh2;
            if (vg < NV) {
                size_t o = (size_t)bg*2334 + (size_t)vg*3;
                out[o+0] = ox; out[o+1] = oy; out[o+2] = oz;
                int slot = -1;
                if (vg == 745) slot = 4; else if (vg == 333) slot = 8;
                else if (vg == 444) slot = 12; else if (vg == 555) slot = 16;
                else if (vg == 672) slot = 20;
                if (slot >= 0) {
                    size_t jb = (size_t)BS*2334 + (size_t)bg*63 + (size_t)slot*3;
                    out[jb+0] = ox; out[jb+1] = oy; out[jb+2] = oz;
                }
            }
        }
    }
}

extern "C" void kernel_launch(void* const* d_in, const int* in_sizes, int n_in,
                              void* d_out, int out_size, void* d_ws, size_t ws_size,
                              hipStream_t stream) {
    (void)in_sizes; (void)n_in; (void)ws_size; (void)out_size;
    const float* root_rot   = (const float*)d_in[0];
    const float* pose       = (const float*)d_in[1];
    const float* shape      = (const float*)d_in[2];
    const float* trans      = (const float*)d_in[3];
    const float* hc         = (const float*)d_in[4];
    const float* hmean      = (const float*)d_in[5];
    const float* shapedirs  = (const float*)d_in[6];
    const float* posedirs   = (const float*)d_in[7];
    const float* v_template = (const float*)d_in[8];
    const float* JR         = (const float*)d_in[9];
    const float* weights    = (const float*)d_in[10];
    float* ws  = (float*)d_ws;
    float* out = (float*)d_out;

    mano_pre<<<dim3(528), dim3(64), 0, stream>>>(shapedirs, v_template, JR, ws);
    mano_batch<<<dim3(BS), dim3(64), 0, stream>>>(root_rot, pose, shape, trans,
                                                  hc, hmean, ws, out);
    mano_verts<<<dim3(64, 13), dim3(256), 0, stream>>>(posedirs, shapedirs, v_template,
                                                       weights, ws, out);
}

// Round 15
// 220.716 us; speedup vs baseline: 1.5872x; 1.0505x over previous
//
#include <hip/hip_runtime.h>

#define BS 4096
#define NV 778
#define NJ 16
#define NC 45

// ws float offsets
#define WS_JRS   0                       // 480 floats: (JR@shapedirs)[j,d,s]
#define WS_JRVT  480                     // 48 floats:  (JR@v_template)[j,d]
#define WS_SE3   528                     // BS*192
#define WS_AT    (528 + BS*192)          // 148*BS, layout [k][b]: k<135 pose-feat,
                                         // 135..144 shape, 145 ones, 146..147 zeros
#define WS_SHIFT (WS_AT + 148*BS)        // BS*4, trans - center

// ---------------- kernel A: batch-independent precompute ----------------
__global__ __launch_bounds__(64) void mano_pre(
    const float* __restrict__ shapedirs, const float* __restrict__ v_template,
    const float* __restrict__ JR, float* __restrict__ ws)
{
    int o = blockIdx.x;          // 0..527
    int lane = threadIdx.x;
    float acc = 0.0f;
    if (o < 480) {
        int j = o / 30, rem = o % 30;
        for (int v = lane; v < NV; v += 64)
            acc += JR[j * NV + v] * shapedirs[v * 30 + rem];
    } else {
        int o2 = o - 480;
        int j = o2 / 3, d = o2 % 3;
        for (int v = lane; v < NV; v += 64)
            acc += JR[j * NV + v] * v_template[v * 3 + d];
    }
    #pragma unroll
    for (int off = 32; off > 0; off >>= 1) acc += __shfl_down(acc, off, 64);
    if (lane == 0) ws[(o < 480) ? (WS_JRS + o) : (WS_JRVT + (o - 480))] = acc;
}

// ---------------- kernel B: per-batch prep (1 wave / batch) ----------------
// R5-verbatim. R6 split and R9 4x-packing were both neutral.
__global__ __launch_bounds__(64) void mano_batch(
    const float* __restrict__ root_rot, const float* __restrict__ pose,
    const float* __restrict__ shape, const float* __restrict__ trans,
    const float* __restrict__ hc, const float* __restrict__ hmean,
    float* __restrict__ ws, float* __restrict__ out)
{
    const int b = blockIdx.x;
    const int t = threadIdx.x;

    __shared__ float s_pose[NC], s_shape[10], s_axis[NC];
    __shared__ float s_rot[135], s_pf[135];
    __shared__ float s_jt[48], s_A[192], s_SE3[192], s_jl[48], s_shift[3];

    if (t < NC) s_pose[t] = pose[b * NC + t];
    if (t < 10) s_shape[t] = shape[b * 10 + t];
    __syncthreads();

    if (t < NC) {
        float a = hmean[t];
        for (int i = 0; i < NC; ++i) a += s_pose[i] * hc[i * NC + t];
        s_axis[t] = a;
    }
    __syncthreads();

    if (t < 15) {   // Rodrigues
        float ax = s_axis[t*3+0], ay = s_axis[t*3+1], az = s_axis[t*3+2];
        float angle = sqrtf(ax*ax + ay*ay + az*az + 1e-12f);
        float inv = 1.0f / angle;
        float ux = ax*inv, uy = ay*inv, uz = az*inv;
        float c = cosf(angle), s = sinf(angle), ic = 1.0f - c;
        float R[9];
        R[0]=c+ic*ux*ux;       R[1]=-s*uz+ic*ux*uy;  R[2]= s*uy+ic*ux*uz;
        R[3]= s*uz+ic*ux*uy;   R[4]=c+ic*uy*uy;      R[5]=-s*ux+ic*uy*uz;
        R[6]=-s*uy+ic*ux*uz;   R[7]= s*ux+ic*uy*uz;  R[8]=c+ic*uz*uz;
        #pragma unroll
        for (int k = 0; k < 9; ++k) {
            s_rot[t*9+k] = R[k];
            s_pf[t*9+k]  = R[k] - ((k==0||k==4||k==8) ? 1.0f : 0.0f);
        }
    }
    if (t < 48) {   // j_tpose via (JR@shapedirs) trick
        float a = ws[WS_JRVT + t];
        #pragma unroll
        for (int s2 = 0; s2 < 10; ++s2) a += ws[WS_JRS + t*10 + s2] * s_shape[s2];
        s_jt[t] = a;
    }
    __syncthreads();

    if (t < NJ) {   // local [R | j - R j]
        float R[9];
        if (t == 0) {
            #pragma unroll
            for (int k = 0; k < 9; ++k) R[k] = root_rot[b*9+k];
        } else {
            #pragma unroll
            for (int k = 0; k < 9; ++k) R[k] = s_rot[(t-1)*9+k];
        }
        float jx = s_jt[t*3+0], jy = s_jt[t*3+1], jz = s_jt[t*3+2];
        #pragma unroll
        for (int r = 0; r < 3; ++r) {
            float jr = (r==0)?jx:((r==1)?jy:jz);
            float ti = jr - (R[r*3+0]*jx + R[r*3+1]*jy + R[r*3+2]*jz);
            s_A[t*12+r*4+0]=R[r*3+0]; s_A[t*12+r*4+1]=R[r*3+1];
            s_A[t*12+r*4+2]=R[r*3+2]; s_A[t*12+r*4+3]=ti;
        }
    }
    __syncthreads();

    if (t == 5) {
        #pragma unroll
        for (int k = 0; k < 12; ++k) s_SE3[k] = s_A[k];
    }
    if (t < 5) {    // 5 chains of depth 3
        float P[12];
        #pragma unroll
        for (int k = 0; k < 12; ++k) P[k] = s_A[k];
        for (int step = 0; step < 3; ++step) {
            int i = t*3 + 1 + step;
            float M[12];
            #pragma unroll
            for (int r = 0; r < 3; ++r) {
                #pragma unroll
                for (int c = 0; c < 3; ++c)
                    M[r*4+c] = P[r*4+0]*s_A[i*12+0*4+c] + P[r*4+1]*s_A[i*12+1*4+c]
                             + P[r*4+2]*s_A[i*12+2*4+c];
                M[r*4+3] = P[r*4+0]*s_A[i*12+3] + P[r*4+1]*s_A[i*12+7]
                         + P[r*4+2]*s_A[i*12+11] + P[r*4+3];
            }
            #pragma unroll
            for (int k = 0; k < 12; ++k) { s_SE3[i*12+k] = M[k]; P[k] = M[k]; }
        }
    }
    __syncthreads();

    if (t < NJ) {   // posed joints
        if (t == 0) { s_jl[0]=s_jt[0]; s_jl[1]=s_jt[1]; s_jl[2]=s_jt[2]; }
        else {
            const int PAR[NJ] = {-1,0,1,2,0,4,5,0,7,8,0,10,11,0,13,14};
            int p = PAR[t];
            float jx = s_jt[t*3+0], jy = s_jt[t*3+1], jz = s_jt[t*3+2];
            #pragma unroll
            for (int r = 0; r < 3; ++r)
                s_jl[t*3+r] = s_SE3[p*12+r*4+0]*jx + s_SE3[p*12+r*4+1]*jy
                            + s_SE3[p*12+r*4+2]*jz + s_SE3[p*12+r*4+3];
        }
    }
    if (t < 3) s_shift[t] = trans[b*3+t] - s_jt[t];
    __syncthreads();

    // ---- stores ----
    for (int k = t; k < 148; k += 64) {
        float val;
        if (k < 135)       val = s_pf[k];
        else if (k < 145)  val = s_shape[k - 135];
        else if (k == 145) val = 1.0f;
        else               val = 0.0f;
        ws[WS_AT + k*BS + b] = val;
    }
    for (int k = t; k < 192; k += 64) ws[WS_SE3 + b*192 + k] = s_SE3[k];
    if (t < 4) ws[WS_SHIFT + b*4 + t] = (t < 3) ? s_shift[t] : 0.0f;
    if (t < 21) {
        const int NO[21] = {0,13,14,15,16,1,2,3,17,4,5,6,18,10,11,12,19,7,8,9,20};
        int src = NO[t];
        if (src < 16) {
            size_t jb = (size_t)BS*2334 + (size_t)b*63 + (size_t)t*3;
            out[jb+0] = s_jl[src*3+0] + s_shift[0];
            out[jb+1] = s_jl[src*3+1] + s_shift[1];
            out[jb+2] = s_jl[src*3+2] + s_shift[2];
        }
    }
}

// ---------------- kernel C: GEMM (K=148) + fused LBS ----------------
// Block: 64 batches x 32 vertices. Thread: 4 batches x 2 STRIDED vertices
// (vi, vi+16) — the proven R12 tile.
// NEW vs R12: LDS shrunk 53.8K -> ~31K for 5 blocks/CU (was 3):
//   - K staged in 4 QUARTERS (40/36/36/36 rows): As[40*68]+Bs[96*44]=27.8K
//   - SE3 staged in TWO 32-batch halves: Ss[32*196]=25.1K; epilogue half 0
//     runs on waves 0-1 (bq<8, wave-uniform), half 1 on waves 2-3.
// FP accumulation order identical to R12 (k ascending groups) -> bit-exact.
// NOTE 1: NO min-occupancy arg in __launch_bounds__ (rounds 1/3: spill).
// NOTE 2: '#pragma unroll 1' on K/quarter loops is LOAD-BEARING (round 4:
//   full unroll -> VGPR 256 + 7.7 GB spill traffic).
// NOTE 3: do NOT hand-pipeline the GEMM loop (round 8: 125->157us).
// NOTE 4: SE3 goes through LDS, NOT global-direct (round 10: 125->136us).
// NOTE 5: VGPR gate: <=96 for 5 waves/SIMD (R12 measured 68).
// NOTE 6: vertex pairing must be STRIDED (vi, vi+16): adjacent pairing makes
//   the B-read stride ≡ 0/16 mod 32 -> 8-way conflict (round 13: 88M).
#define AS_LD 68        // A row stride: 64 data + 4 pad
#define BS_LD 44        // B col stride: 40 rows max + 4 pad; 3*44=132 ≡ 4 (mod 32)
#define SS_LD 196       // SE3 row stride: 4*196 ≡ 16 (mod 32) -> 2-way (free)

__global__ __launch_bounds__(256) void mano_verts(
    const float* __restrict__ posedirs, const float* __restrict__ shapedirs,
    const float* __restrict__ v_template, const float* __restrict__ weights,
    const float* __restrict__ ws, float* __restrict__ out)
{
    const int btile = blockIdx.x;   // 0..63
    const int vtile = blockIdx.y;   // 0..24
    const int t = threadIdx.x;
    const int b0 = btile * 64;
    const int v0 = vtile * 32;

    __shared__ union {
        struct { float As[40*AS_LD]; float Bs[96*BS_LD]; } g; // 10880+16896 B
        float Ss[32*SS_LD];                                   // 25088 B
    } u;
    __shared__ float s_w[32*17];    // weights tile, stride 17
    __shared__ float s_sh[64*4];    // shift tile

    // ---- stage weights + shift (persist across phases) ----
    for (int idx = t; idx < 32*16; idx += 256) {
        int vl = idx >> 4, j = idx & 15;
        int vg = v0 + vl; if (vg > NV-1) vg = NV-1;
        s_w[vl*17 + j] = weights[vg*16 + j];
    }
    s_sh[t] = ws[WS_SHIFT + b0*4 + t];

    const int vi = t & 15, bq = t >> 4;
    const int bq4 = bq * 4;
    const float* At = ws + WS_AT + b0;

    float accA[4][3], accB[4][3];
    #pragma unroll
    for (int i = 0; i < 4; ++i)
        #pragma unroll
        for (int c = 0; c < 3; ++c) { accA[i][c] = 0.0f; accB[i][c] = 0.0f; }

    // ============ four K-quarters: stage A+B, then GEMM ============
    #pragma unroll 1
    for (int q = 0; q < 4; ++q) {
        const int r0 = q ? (36*q + 4) : 0;   // 0,40,76,112
        const int nq = q ? 9 : 10;           // float4 groups this quarter
        const int nr = nq * 4;               // rows this quarter

        // ---- stage B: 96 cols x nq groups (const-divisor layout) ----
        for (int idx = t; idx < 96*10; idx += 256) {
            int col = idx / 10, kq = idx - col*10;
            if (kq < nq) {
                int kk = kq * 4;
                int vg = v0 + col/3; if (vg > NV-1) vg = NV-1;
                int d = col % 3;
                float tmp[4];
                #pragma unroll
                for (int uu = 0; uu < 4; ++uu) {
                    int k = r0 + kk + uu;
                    float x;
                    if (k < 135)       x = posedirs[vg*405 + d*135 + k];
                    else if (k < 145)  x = shapedirs[vg*30 + d*10 + (k-135)];
                    else if (k == 145) x = v_template[vg*3 + d];
                    else               x = 0.0f;
                    tmp[uu] = x;
                }
                *(float4*)&u.g.Bs[col*BS_LD + kk] =
                    make_float4(tmp[0], tmp[1], tmp[2], tmp[3]);
            }
        }
        // ---- stage A: nr rows, float4 over batches ----
        for (int idx = t; idx < 40*16; idx += 256) {
            int kr = idx >> 4, j4 = (idx & 15) << 2;
            if (kr < nr)
                *(float4*)&u.g.As[kr*AS_LD + j4] =
                    *(const float4*)&At[(size_t)(r0+kr)*BS + j4];
        }
        __syncthreads();

        // ---- GEMM over this quarter (R12 body, BS_LD=44) ----
        const float* BvA = &u.g.Bs[(vi*3)*BS_LD];
        const float* BvB = &u.g.Bs[((vi+16)*3)*BS_LD];
        #pragma unroll 1
        for (int r = 0; r < nq; ++r) {
            const int kk = r * 4;
            float a_[4][4];   // a_[kq][ib]
            #pragma unroll
            for (int kq = 0; kq < 4; ++kq)
                *(float4*)&a_[kq][0] = *(const float4*)&u.g.As[(kk+kq)*AS_LD + bq4];
            float bA[3][4], bB[3][4];   // [c][kq]
            #pragma unroll
            for (int c = 0; c < 3; ++c) {
                *(float4*)&bA[c][0] = *(const float4*)&BvA[c*BS_LD + kk];
                *(float4*)&bB[c][0] = *(const float4*)&BvB[c*BS_LD + kk];
            }
            #pragma unroll
            for (int ib = 0; ib < 4; ++ib)
                #pragma unroll
                for (int c = 0; c < 3; ++c) {
                    accA[ib][c] += a_[0][ib]*bA[c][0] + a_[1][ib]*bA[c][1]
                                 + a_[2][ib]*bA[c][2] + a_[3][ib]*bA[c][3];
                    accB[ib][c] += a_[0][ib]*bB[c][0] + a_[1][ib]*bB[c][1]
                                 + a_[2][ib]*bB[c][2] + a_[3][ib]*bB[c][3];
                }
        }
        __syncthreads();
    }

    // ============ epilogue in two 32-batch halves ============
    // Thread's 4 batches (bq4..bq4+3) all lie in one half: bq<8 -> half 0
    // (waves 0-1), bq>=8 -> half 1 (waves 2-3). Wave-uniform guard.
    const float* se3w = ws + WS_SE3 + (size_t)b0*192;
    #pragma unroll 1
    for (int h2 = 0; h2 < 2; ++h2) {
        // ---- stage 32 batches of SE3 (all threads help) ----
        for (int idx = t; idx < 32*48; idx += 256) {
            int b = idx / 48, q4 = (idx - b*48) << 2;
            *(float4*)&u.Ss[b*SS_LD + q4] =
                *(const float4*)&se3w[(size_t)(h2*32 + b)*192 + q4];
        }
        __syncthreads();

        if ((bq >> 3) == h2) {
            #pragma unroll
            for (int ib = 0; ib < 4; ++ib) {
                const int bl = bq4 + ib;          // 0..63 global in tile
                const int bg = b0 + bl;
                const float* S = &u.Ss[(bl & 31)*SS_LD];
                float M0[12], M1[12];
                #pragma unroll
                for (int k = 0; k < 12; ++k) { M0[k] = 0.0f; M1[k] = 0.0f; }
                #pragma unroll 2
                for (int j = 0; j < 16; ++j) {   // unroll 2: bound loads in flight
                    float4 r0v = *(const float4*)&S[j*12 + 0];
                    float4 r1v = *(const float4*)&S[j*12 + 4];
                    float4 r2v = *(const float4*)&S[j*12 + 8];
                    float wA = s_w[vi*17 + j];
                    float wB = s_w[(vi+16)*17 + j];
                    M0[0] += wA*r0v.x; M0[1] += wA*r0v.y; M0[2]  += wA*r0v.z; M0[3]  += wA*r0v.w;
                    M0[4] += wA*r1v.x; M0[5] += wA*r1v.y; M0[6]  += wA*r1v.z; M0[7]  += wA*r1v.w;
                    M0[8] += wA*r2v.x; M0[9] += wA*r2v.y; M0[10] += wA*r2v.z; M0[11] += wA*r2v.w;
                    M1[0] += wB*r0v.x; M1[1] += wB*r0v.y; M1[2]  += wB*r0v.z; M1[3]  += wB*r0v.w;
                    M1[4] += wB*r1v.x; M1[5] += wB*r1v.y; M1[6]  += wB*r1v.z; M1[7]  += wB*r1v.w;
                    M1[8] += wB*r2v.x; M1[9] += wB*r2v.y; M1[10] += wB*r2v.z; M1[11] += wB*r2v.w;
                }
                float sh0 = s_sh[bl*4+0], sh1 = s_sh[bl*4+1], sh2 = s_sh[bl*4+2];
                {
                    const int vgA = v0 + vi;
                    float x = accA[ib][0], y = accA[ib][1], z = accA[ib][2];
                    float ox = M0[0]*x + M0[1]*y + M0[2] *z + M0[3]  + sh0;
                    float oy = M0[4]*x + M0[5]*y + M0[6] *z + M0[7]  + sh1;
                    float oz = M0[8]*x + M0[9]*y + M0[10]*z + M0[11] + sh2;
                    if (vgA < NV) {
                        size_t o = (size_t)bg*2334 + (size_t)vgA*3;
                        out[o+0] = ox; out[o+1] = oy; out[o+2] = oz;
                        int slot = -1;
                        if (vgA == 745) slot = 4; else if (vgA == 333) slot = 8;
                        else if (vgA == 444) slot = 12; else if (vgA == 555) slot = 16;
                        else if (vgA == 672) slot = 20;
                        if (slot >= 0) {
                            size_t jb = (size_t)BS*2334 + (size_t)bg*63 + (size_t)slot*3;
                            out[jb+0] = ox; out[jb+1] = oy; out[jb+2] = oz;
                        }
                    }
                }
                {
                    const int vgB = v0 + 16 + vi;
                    float x = accB[ib][0], y = accB[ib][1], z = accB[ib][2];
                    float ox = M1[0]*x + M1[1]*y + M1[2] *z + M1[3]  + sh0;
                    float oy = M1[4]*x + M1[5]*y + M1[6] *z + M1[7]  + sh1;
                    float oz = M1[8]*x + M1[9]*y + M1[10]*z + M1[11] + sh2;
                    if (vgB < NV) {
                        size_t o = (size_t)bg*2334 + (size_t)vgB*3;
                        out[o+0] = ox; out[o+1] = oy; out[o+2] = oz;
                        int slot = -1;
                        if (vgB == 745) slot = 4; else if (vgB == 333) slot = 8;
                        else if (vgB == 444) slot = 12; else if (vgB == 555) slot = 16;
                        else if (vgB == 672) slot = 20;
                        if (slot >= 0) {
                            size_t jb = (size_t)BS*2334 + (size_t)bg*63 + (size_t)slot*3;
                            out[jb+0] = ox; out[jb+1] = oy; out[jb+2] = oz;
                        }
                    }
                }
            }
        }
        __syncthreads();
    }
}

extern "C" void kernel_launch(void* const* d_in, const int* in_sizes, int n_in,
                              void* d_out, int out_size, void* d_ws, size_t ws_size,
                              hipStream_t stream) {
    (void)in_sizes; (void)n_in; (void)ws_size; (void)out_size;
    const float* root_rot   = (const float*)d_in[0];
    const float* pose       = (const float*)d_in[1];
    const float* shape      = (const float*)d_in[2];
    const float* trans      = (const float*)d_in[3];
    const float* hc         = (const float*)d_in[4];
    const float* hmean      = (const float*)d_in[5];
    const float* shapedirs  = (const float*)d_in[6];
    const float* posedirs   = (const float*)d_in[7];
    const float* v_template = (const float*)d_in[8];
    const float* JR         = (const float*)d_in[9];
    const float* weights    = (const float*)d_in[10];
    float* ws  = (float*)d_ws;
    float* out = (float*)d_out;

    mano_pre<<<dim3(528), dim3(64), 0, stream>>>(shapedirs, v_template, JR, ws);
    mano_batch<<<dim3(BS), dim3(64), 0, stream>>>(root_rot, pose, shape, trans,
                                                  hc, hmean, ws, out);
    mano_verts<<<dim3(64, 25), dim3(256), 0, stream>>>(posedirs, shapedirs, v_template,
                                                       weights, ws, out);
}

// Round 16
// 195.651 us; speedup vs baseline: 1.7905x; 1.1281x over previous
//
#include <hip/hip_runtime.h>

#define BS 4096
#define NV 778
#define NJ 16
#define NC 45

// ws float offsets
#define WS_JRS   0                       // 480 floats: (JR@shapedirs)[j,d,s]
#define WS_JRVT  480                     // 48 floats:  (JR@v_template)[j,d]
#define WS_SE3   528                     // BS*192
#define WS_AT    (528 + BS*192)          // 148*BS, layout [k][b]: k<135 pose-feat,
                                         // 135..144 shape, 145 ones, 146..147 zeros
#define WS_SHIFT (WS_AT + 148*BS)        // BS*4, trans - center

// ---------------- kernel A: batch-independent precompute ----------------
__global__ __launch_bounds__(64) void mano_pre(
    const float* __restrict__ shapedirs, const float* __restrict__ v_template,
    const float* __restrict__ JR, float* __restrict__ ws)
{
    int o = blockIdx.x;          // 0..527
    int lane = threadIdx.x;
    float acc = 0.0f;
    if (o < 480) {
        int j = o / 30, rem = o % 30;
        for (int v = lane; v < NV; v += 64)
            acc += JR[j * NV + v] * shapedirs[v * 30 + rem];
    } else {
        int o2 = o - 480;
        int j = o2 / 3, d = o2 % 3;
        for (int v = lane; v < NV; v += 64)
            acc += JR[j * NV + v] * v_template[v * 3 + d];
    }
    #pragma unroll
    for (int off = 32; off > 0; off >>= 1) acc += __shfl_down(acc, off, 64);
    if (lane == 0) ws[(o < 480) ? (WS_JRS + o) : (WS_JRVT + (o - 480))] = acc;
}

// ---------------- kernel B: per-batch prep (1 wave / batch) ----------------
// R5-verbatim. R6 split and R9 4x-packing were both neutral: this kernel's
// cost is dominated by fixed per-launch overhead, not its schedule.
__global__ __launch_bounds__(64) void mano_batch(
    const float* __restrict__ root_rot, const float* __restrict__ pose,
    const float* __restrict__ shape, const float* __restrict__ trans,
    const float* __restrict__ hc, const float* __restrict__ hmean,
    float* __restrict__ ws, float* __restrict__ out)
{
    const int b = blockIdx.x;
    const int t = threadIdx.x;

    __shared__ float s_pose[NC], s_shape[10], s_axis[NC];
    __shared__ float s_rot[135], s_pf[135];
    __shared__ float s_jt[48], s_A[192], s_SE3[192], s_jl[48], s_shift[3];

    if (t < NC) s_pose[t] = pose[b * NC + t];
    if (t < 10) s_shape[t] = shape[b * 10 + t];
    __syncthreads();

    if (t < NC) {
        float a = hmean[t];
        for (int i = 0; i < NC; ++i) a += s_pose[i] * hc[i * NC + t];
        s_axis[t] = a;
    }
    __syncthreads();

    if (t < 15) {   // Rodrigues
        float ax = s_axis[t*3+0], ay = s_axis[t*3+1], az = s_axis[t*3+2];
        float angle = sqrtf(ax*ax + ay*ay + az*az + 1e-12f);
        float inv = 1.0f / angle;
        float ux = ax*inv, uy = ay*inv, uz = az*inv;
        float c = cosf(angle), s = sinf(angle), ic = 1.0f - c;
        float R[9];
        R[0]=c+ic*ux*ux;       R[1]=-s*uz+ic*ux*uy;  R[2]= s*uy+ic*ux*uz;
        R[3]= s*uz+ic*ux*uy;   R[4]=c+ic*uy*uy;      R[5]=-s*ux+ic*uy*uz;
        R[6]=-s*uy+ic*ux*uz;   R[7]= s*ux+ic*uy*uz;  R[8]=c+ic*uz*uz;
        #pragma unroll
        for (int k = 0; k < 9; ++k) {
            s_rot[t*9+k] = R[k];
            s_pf[t*9+k]  = R[k] - ((k==0||k==4||k==8) ? 1.0f : 0.0f);
        }
    }
    if (t < 48) {   // j_tpose via (JR@shapedirs) trick
        float a = ws[WS_JRVT + t];
        #pragma unroll
        for (int s2 = 0; s2 < 10; ++s2) a += ws[WS_JRS + t*10 + s2] * s_shape[s2];
        s_jt[t] = a;
    }
    __syncthreads();

    if (t < NJ) {   // local [R | j - R j]
        float R[9];
        if (t == 0) {
            #pragma unroll
            for (int k = 0; k < 9; ++k) R[k] = root_rot[b*9+k];
        } else {
            #pragma unroll
            for (int k = 0; k < 9; ++k) R[k] = s_rot[(t-1)*9+k];
        }
        float jx = s_jt[t*3+0], jy = s_jt[t*3+1], jz = s_jt[t*3+2];
        #pragma unroll
        for (int r = 0; r < 3; ++r) {
            float jr = (r==0)?jx:((r==1)?jy:jz);
            float ti = jr - (R[r*3+0]*jx + R[r*3+1]*jy + R[r*3+2]*jz);
            s_A[t*12+r*4+0]=R[r*3+0]; s_A[t*12+r*4+1]=R[r*3+1];
            s_A[t*12+r*4+2]=R[r*3+2]; s_A[t*12+r*4+3]=ti;
        }
    }
    __syncthreads();

    if (t == 5) {
        #pragma unroll
        for (int k = 0; k < 12; ++k) s_SE3[k] = s_A[k];
    }
    if (t < 5) {    // 5 chains of depth 3
        float P[12];
        #pragma unroll
        for (int k = 0; k < 12; ++k) P[k] = s_A[k];
        for (int step = 0; step < 3; ++step) {
            int i = t*3 + 1 + step;
            float M[12];
            #pragma unroll
            for (int r = 0; r < 3; ++r) {
                #pragma unroll
                for (int c = 0; c < 3; ++c)
                    M[r*4+c] = P[r*4+0]*s_A[i*12+0*4+c] + P[r*4+1]*s_A[i*12+1*4+c]
                             + P[r*4+2]*s_A[i*12+2*4+c];
                M[r*4+3] = P[r*4+0]*s_A[i*12+3] + P[r*4+1]*s_A[i*12+7]
                         + P[r*4+2]*s_A[i*12+11] + P[r*4+3];
            }
            #pragma unroll
            for (int k = 0; k < 12; ++k) { s_SE3[i*12+k] = M[k]; P[k] = M[k]; }
        }
    }
    __syncthreads();

    if (t < NJ) {   // posed joints
        if (t == 0) { s_jl[0]=s_jt[0]; s_jl[1]=s_jt[1]; s_jl[2]=s_jt[2]; }
        else {
            const int PAR[NJ] = {-1,0,1,2,0,4,5,0,7,8,0,10,11,0,13,14};
            int p = PAR[t];
            float jx = s_jt[t*3+0], jy = s_jt[t*3+1], jz = s_jt[t*3+2];
            #pragma unroll
            for (int r = 0; r < 3; ++r)
                s_jl[t*3+r] = s_SE3[p*12+r*4+0]*jx + s_SE3[p*12+r*4+1]*jy
                            + s_SE3[p*12+r*4+2]*jz + s_SE3[p*12+r*4+3];
        }
    }
    if (t < 3) s_shift[t] = trans[b*3+t] - s_jt[t];
    __syncthreads();

    // ---- stores ----
    for (int k = t; k < 148; k += 64) {
        float val;
        if (k < 135)       val = s_pf[k];
        else if (k < 145)  val = s_shape[k - 135];
        else if (k == 145) val = 1.0f;
        else               val = 0.0f;
        ws[WS_AT + k*BS + b] = val;
    }
    for (int k = t; k < 192; k += 64) ws[WS_SE3 + b*192 + k] = s_SE3[k];
    if (t < 4) ws[WS_SHIFT + b*4 + t] = (t < 3) ? s_shift[t] : 0.0f;
    if (t < 21) {
        const int NO[21] = {0,13,14,15,16,1,2,3,17,4,5,6,18,10,11,12,19,7,8,9,20};
        int src = NO[t];
        if (src < 16) {
            size_t jb = (size_t)BS*2334 + (size_t)b*63 + (size_t)t*3;
            out[jb+0] = s_jl[src*3+0] + s_shift[0];
            out[jb+1] = s_jl[src*3+1] + s_shift[1];
            out[jb+2] = s_jl[src*3+2] + s_shift[2];
        }
    }
}

// ---------------- kernel C: GEMM (K=148) + fused LBS ----------------
// Block: 64 batches x 32 vertices. Thread: 4 batches x 2 STRIDED vertices
// (vi, vi+16). MEASURED LOCAL OPTIMUM (R12: verts ~111us, total 197.1us).
// Do-not-retry ledger (all measured on MI355X, rounds 1-15):
//   - min-occupancy arg in __launch_bounds__: VGPR cap -> GB-scale spill
//     (R1: 64 VGPR/320MB, R3: 84 VGPR/11.5GB).
//   - full unroll of 18/19-iter K-loops: VGPR 256 + 7.7GB spill (R4).
//     '#pragma unroll 1' on K-pass loops is LOAD-BEARING.
//   - hand software-pipelining (ping-pong regs): 125->157us; TLP at 12
//     waves/CU already hides LDS latency; VGPR 80->108, occ 29->21 (R8).
//   - SE3 epilogue from global instead of LDS: 125->136us even with
//     conflicts at 25K; L2 broadcast reads cost more than LDS+2-way (R10).
//   - 4 verts/thread ADJACENT: B-stride 12*BS_LD ≡ 0/16 mod 32 -> 8-way
//     conflict, 88M cycles, 266us (R13). Padding cannot fix adjacency.
//   - 4 verts/thread STRIDED (64x64 tile): conflicts 16M, grid 832 blocks
//     = 3.25/CU tail, 150us (R14).
//   - K-quarters + SE3-half-staging for 5 blocks/CU (31KB LDS): occupancy
//     did NOT rise (26.8 == R12's 26.4 -> never LDS-capped); +5 barriers
//     and half-idle epilogue cost 111->137.5us (R15).
// Floor model: ~650 ds_read_b128/thread x ~12cyc on the CU-shared LDS pipe
// ~= 90-100us; measured 111us incl. ~11% conflict overhead + barriers.
#define AS_ROWS 76
#define AS_LD   68      // A row stride: 64 data + 4 pad
#define BS_LD   76      // B col stride: rows per K-half; 3*76=228 ≡ 4 (mod 32)
#define SS_LD   196     // SE3 row stride: 4*196 ≡ 16 (mod 32) -> 2-way (free)

__global__ __launch_bounds__(256) void mano_verts(
    const float* __restrict__ posedirs, const float* __restrict__ shapedirs,
    const float* __restrict__ v_template, const float* __restrict__ weights,
    const float* __restrict__ ws, float* __restrict__ out)
{
    const int btile = blockIdx.x;   // 0..63
    const int vtile = blockIdx.y;   // 0..24
    const int t = threadIdx.x;
    const int b0 = btile * 64;
    const int v0 = vtile * 32;

    __shared__ union {
        struct { float As[76*AS_LD]; float Bs[96*BS_LD]; } g; // 20672+29184 B
        float Ss[64*SS_LD];                                   // 50176 B
    } u;
    __shared__ float s_w[32*17];    // weights tile, stride 17
    __shared__ float s_sh[64*4];    // shift tile

    // ---- stage weights (512 entries) + shift ----
    for (int idx = t; idx < 32*16; idx += 256) {
        int vl = idx >> 4, j = idx & 15;
        int vg = v0 + vl; if (vg > NV-1) vg = NV-1;
        s_w[vl*17 + j] = weights[vg*16 + j];
    }
    s_sh[t] = ws[WS_SHIFT + b0*4 + t];

    const int vi = t & 15, bq = t >> 4;
    const int bq4 = bq * 4;
    const float* At = ws + WS_AT + b0;

    float accA[4][3], accB[4][3];
    #pragma unroll
    for (int i = 0; i < 4; ++i)
        #pragma unroll
        for (int c = 0; c < 3; ++c) { accA[i][c] = 0.0f; accB[i][c] = 0.0f; }

    // ================= two K-halves: stage A+B, then GEMM =================
    #pragma unroll 1
    for (int h = 0; h < 2; ++h) {
        const int r0 = h ? 76 : 0;          // global K row base
        const int NQ = h ? 18 : 19;         // float4 groups in this half

        // ---- stage B: [col=96][BS_LD], cols = 32 verts x 3 dims ----
        for (int idx = t; idx < 96*NQ; idx += 256) {
            int col = idx / NQ, kq = idx - col*NQ;
            int kk = kq * 4;
            int vg = v0 + col/3; if (vg > NV-1) vg = NV-1;
            int d = col % 3;
            float tmp[4];
            #pragma unroll
            for (int uu = 0; uu < 4; ++uu) {
                int k = r0 + kk + uu;
                float x;
                if (k < 135)       x = posedirs[vg*405 + d*135 + k];
                else if (k < 145)  x = shapedirs[vg*30 + d*10 + (k-135)];
                else if (k == 145) x = v_template[vg*3 + d];
                else               x = 0.0f;
                tmp[uu] = x;
            }
            *(float4*)&u.g.Bs[col*BS_LD + kk] = make_float4(tmp[0], tmp[1], tmp[2], tmp[3]);
        }
        // ---- stage A: rows r0..r0+NQ*4-1, float4 over batches ----
        for (int idx = t; idx < NQ*4*16; idx += 256) {
            int kr = idx >> 4, j4 = (idx & 15) << 2;
            *(float4*)&u.g.As[kr*AS_LD + j4] = *(const float4*)&At[(size_t)(r0+kr)*BS + j4];
        }
        __syncthreads();

        // ---- GEMM over this half ----
        const float* BvA = &u.g.Bs[(vi*3)*BS_LD];
        const float* BvB = &u.g.Bs[((vi+16)*3)*BS_LD];
        #pragma unroll 1
        for (int r = 0; r < NQ; ++r) {
            const int kk = r * 4;
            float a_[4][4];   // a_[kq][ib]
            #pragma unroll
            for (int kq = 0; kq < 4; ++kq)
                *(float4*)&a_[kq][0] = *(const float4*)&u.g.As[(kk+kq)*AS_LD + bq4];
            float bA[3][4], bB[3][4];   // [c][kq]
            #pragma unroll
            for (int c = 0; c < 3; ++c) {
                *(float4*)&bA[c][0] = *(const float4*)&BvA[c*BS_LD + kk];
                *(float4*)&bB[c][0] = *(const float4*)&BvB[c*BS_LD + kk];
            }
            #pragma unroll
            for (int ib = 0; ib < 4; ++ib)
                #pragma unroll
                for (int c = 0; c < 3; ++c) {
                    accA[ib][c] += a_[0][ib]*bA[c][0] + a_[1][ib]*bA[c][1]
                                 + a_[2][ib]*bA[c][2] + a_[3][ib]*bA[c][3];
                    accB[ib][c] += a_[0][ib]*bB[c][0] + a_[1][ib]*bB[c][1]
                                 + a_[2][ib]*bB[c][2] + a_[3][ib]*bB[c][3];
                }
        }
        __syncthreads();
    }

    // ---- stage SE3 tile into (reused) LDS: Ss[b][SS_LD], 48 float4/batch ----
    const float* se3w = ws + WS_SE3 + (size_t)b0*192;
    for (int idx = t; idx < 64*48; idx += 256) {
        int b = idx / 48, q4 = (idx - b*48) << 2;
        *(float4*)&u.Ss[b*SS_LD + q4] = *(const float4*)&se3w[b*192 + q4];
    }
    __syncthreads();

    // ---- LBS epilogue: SE3 reads shared by both vertices ----
    #pragma unroll
    for (int ib = 0; ib < 4; ++ib) {
        const int bl = bq4 + ib;
        const int bg = b0 + bl;
        const float* S = &u.Ss[bl*SS_LD];
        float M0[12], M1[12];
        #pragma unroll
        for (int k = 0; k < 12; ++k) { M0[k] = 0.0f; M1[k] = 0.0f; }
        #pragma unroll 2
        for (int j = 0; j < 16; ++j) {   // unroll 2: bound loads in flight
            float4 r0 = *(const float4*)&S[j*12 + 0];
            float4 r1 = *(const float4*)&S[j*12 + 4];
            float4 r2 = *(const float4*)&S[j*12 + 8];
            float wA = s_w[vi*17 + j];
            float wB = s_w[(vi+16)*17 + j];
            M0[0] += wA*r0.x; M0[1] += wA*r0.y; M0[2]  += wA*r0.z; M0[3]  += wA*r0.w;
            M0[4] += wA*r1.x; M0[5] += wA*r1.y; M0[6]  += wA*r1.z; M0[7]  += wA*r1.w;
            M0[8] += wA*r2.x; M0[9] += wA*r2.y; M0[10] += wA*r2.z; M0[11] += wA*r2.w;
            M1[0] += wB*r0.x; M1[1] += wB*r0.y; M1[2]  += wB*r0.z; M1[3]  += wB*r0.w;
            M1[4] += wB*r1.x; M1[5] += wB*r1.y; M1[6]  += wB*r1.z; M1[7]  += wB*r1.w;
            M1[8] += wB*r2.x; M1[9] += wB*r2.y; M1[10] += wB*r2.z; M1[11] += wB*r2.w;
        }
        float sh0 = s_sh[bl*4+0], sh1 = s_sh[bl*4+1], sh2 = s_sh[bl*4+2];
        {
            const int vgA = v0 + vi;
            float x = accA[ib][0], y = accA[ib][1], z = accA[ib][2];
            float ox = M0[0]*x + M0[1]*y + M0[2] *z + M0[3]  + sh0;
            float oy = M0[4]*x + M0[5]*y + M0[6] *z + M0[7]  + sh1;
            float oz = M0[8]*x + M0[9]*y + M0[10]*z + M0[11] + sh2;
            if (vgA < NV) {
                size_t o = (size_t)bg*2334 + (size_t)vgA*3;
                out[o+0] = ox; out[o+1] = oy; out[o+2] = oz;
                int slotA = -1;
                if (vgA == 745) slotA = 4; else if (vgA == 333) slotA = 8;
                else if (vgA == 444) slotA = 12; else if (vgA == 555) slotA = 16;
                else if (vgA == 672) slotA = 20;
                if (slotA >= 0) {
                    size_t jb = (size_t)BS*2334 + (size_t)bg*63 + (size_t)slotA*3;
                    out[jb+0] = ox; out[jb+1] = oy; out[jb+2] = oz;
                }
            }
        }
        {
            const int vgB = v0 + 16 + vi;
            float x = accB[ib][0], y = accB[ib][1], z = accB[ib][2];
            float ox = M1[0]*x + M1[1]*y + M1[2] *z + M1[3]  + sh0;
            float oy = M1[4]*x + M1[5]*y + M1[6] *z + M1[7]  + sh1;
            float oz = M1[8]*x + M1[9]*y + M1[10]*z + M1[11] + sh2;
            if (vgB < NV) {
                size_t o = (size_t)bg*2334 + (size_t)vgB*3;
                out[o+0] = ox; out[o+1] = oy; out[o+2] = oz;
                int slotB = -1;
                if (vgB == 745) slotB = 4; else if (vgB == 333) slotB = 8;
                else if (vgB == 444) slotB = 12; else if (vgB == 555) slotB = 16;
                else if (vgB == 672) slotB = 20;
                if (slotB >= 0) {
                    size_t jb = (size_t)BS*2334 + (size_t)bg*63 + (size_t)slotB*3;
                    out[jb+0] = ox; out[jb+1] = oy; out[jb+2] = oz;
                }
            }
        }
    }
}

extern "C" void kernel_launch(void* const* d_in, const int* in_sizes, int n_in,
                              void* d_out, int out_size, void* d_ws, size_t ws_size,
                              hipStream_t stream) {
    (void)in_sizes; (void)n_in; (void)ws_size; (void)out_size;
    const float* root_rot   = (const float*)d_in[0];
    const float* pose       = (const float*)d_in[1];
    const float* shape      = (const float*)d_in[2];
    const float* trans      = (const float*)d_in[3];
    const float* hc         = (const float*)d_in[4];
    const float* hmean      = (const float*)d_in[5];
    const float* shapedirs  = (const float*)d_in[6];
    const float* posedirs   = (const float*)d_in[7];
    const float* v_template = (const float*)d_in[8];
    const float* JR         = (const float*)d_in[9];
    const float* weights    = (const float*)d_in[10];
    float* ws  = (float*)d_ws;
    float* out = (float*)d_out;

    mano_pre<<<dim3(528), dim3(64), 0, stream>>>(shapedirs, v_template, JR, ws);
    mano_batch<<<dim3(BS), dim3(64), 0, stream>>>(root_rot, pose, shape, trans,
                                                  hc, hmean, ws, out);
    mano_verts<<<dim3(64, 25), dim3(256), 0, stream>>>(posedirs, shapedirs, v_template,
                                                       weights, ws, out);
}